// Round 2
// baseline (950.559 us; speedup 1.0000x reference)
//
#include <hip/hip_runtime.h>
#include <math.h>

// ---------------- constants ----------------
constexpr int B_ = 4, T_ = 1024, C_ = 768, H_ = 12, N_ = 64;
constexpr int BT_ = B_ * T_;                    // 4096
constexpr size_t BTC = (size_t)BT_ * C_;        // 3145728
constexpr float EPS_GN = 0.00064f;

typedef __attribute__((ext_vector_type(8))) short bf16x8;
typedef __attribute__((ext_vector_type(4))) float f32x4;
typedef __attribute__((ext_vector_type(4))) unsigned short u16x4;

#define DEVFN static __device__ __forceinline__

DEVFN unsigned short f2bf(float f) {
    unsigned u = __float_as_uint(f);
    unsigned r = u + 0x7FFFu + ((u >> 16) & 1u);
    return (unsigned short)(r >> 16);
}

template<int CTRL>
DEVFN float dppadd(float x) {
    // x += lane-permuted x (quad_perm), VALU-speed
    return x + __int_as_float(__builtin_amdgcn_update_dpp(0, __float_as_int(x), CTRL, 0xF, 0xF, true));
}
#define SWZ_ADD(x, imm) ((x) + __int_as_float(__builtin_amdgcn_ds_swizzle(__float_as_int(x), (imm))))

// full 64-lane sum, result in all lanes
DEVFN float red64(float x) {
    x = dppadd<0xB1>(x);        // xor 1 (quad_perm [1,0,3,2])
    x = dppadd<0x4E>(x);        // xor 2 (quad_perm [2,3,0,1])
    x = SWZ_ADD(x, 0x101F);     // xor 4
    x = SWZ_ADD(x, 0x201F);     // xor 8
    x = SWZ_ADD(x, 0x401F);     // xor 16
    x += __shfl_xor(x, 32, 64); // xor 32
    return x;
}

// 4 independent reductions, stage-interleaved so the latencies pipeline
DEVFN void red64_4(float& a, float& b, float& c, float& d) {
    a = dppadd<0xB1>(a); b = dppadd<0xB1>(b); c = dppadd<0xB1>(c); d = dppadd<0xB1>(d);
    a = dppadd<0x4E>(a); b = dppadd<0x4E>(b); c = dppadd<0x4E>(c); d = dppadd<0x4E>(d);
    a = SWZ_ADD(a, 0x101F); b = SWZ_ADD(b, 0x101F); c = SWZ_ADD(c, 0x101F); d = SWZ_ADD(d, 0x101F);
    a = SWZ_ADD(a, 0x201F); b = SWZ_ADD(b, 0x201F); c = SWZ_ADD(c, 0x201F); d = SWZ_ADD(d, 0x201F);
    a = SWZ_ADD(a, 0x401F); b = SWZ_ADD(b, 0x401F); c = SWZ_ADD(c, 0x401F); d = SWZ_ADD(d, 0x401F);
    a += __shfl_xor(a, 32, 64); b += __shfl_xor(b, 32, 64);
    c += __shfl_xor(c, 32, 64); d += __shfl_xor(d, 32, 64);
}

DEVFN f32x4 mfma16(bf16x8 a, bf16x8 b, f32x4 c) {
    return __builtin_amdgcn_mfma_f32_16x16x32_bf16(a, b, c, 0, 0, 0);
}

// ---------------- kernel 1: timeshift + 6 mixes -> bf16 ----------------
__global__ __launch_bounds__(256) void k_prep(const float* __restrict__ x,
    const float* __restrict__ m0, const float* __restrict__ m1, const float* __restrict__ m2,
    const float* __restrict__ m3, const float* __restrict__ m4, const float* __restrict__ m5,
    unsigned short* __restrict__ X6)
{
    int gid = blockIdx.x * 256 + threadIdx.x;   // BTC/4 threads
    int i4 = gid * 4;
    int bt = i4 / C_;
    int c  = i4 - bt * C_;
    const float4 xv = *(const float4*)(x + (size_t)bt * C_ + c);
    float px = 0.f, py = 0.f, pz = 0.f, pw = 0.f;
    if ((bt % T_) != 0) {
        const float4 p = *(const float4*)(x + (size_t)(bt - 1) * C_ + c);
        px = p.x; py = p.y; pz = p.z; pw = p.w;
    }
    float d0 = px - xv.x, d1 = py - xv.y, d2 = pz - xv.z, d3 = pw - xv.w;
    const float* mixes[6] = {m0, m1, m2, m3, m4, m5};
#pragma unroll
    for (int m = 0; m < 6; ++m) {
        const float4 mv = *(const float4*)(mixes[m] + c);
        u16x4 pk;
        pk[0] = f2bf(fmaf(d0, mv.x, xv.x));
        pk[1] = f2bf(fmaf(d1, mv.y, xv.y));
        pk[2] = f2bf(fmaf(d2, mv.z, xv.z));
        pk[3] = f2bf(fmaf(d3, mv.w, xv.w));
        *(u16x4*)(X6 + (size_t)m * BTC + (size_t)bt * C_ + c) = pk;
    }
}

// ---------------- kernel 2: fp32 W[R][Cc] -> bf16 W^T[Cc][R] ----------------
__global__ __launch_bounds__(256) void k_transpose(const float* __restrict__ W,
    unsigned short* __restrict__ WT, int R, int Cc)
{
    __shared__ float tile[32][33];
    int tx = threadIdx.x & 31, ty = threadIdx.x >> 5;   // ty 0..7
#pragma unroll
    for (int j = 0; j < 4; ++j) {
        int rr = blockIdx.y * 32 + ty + j * 8;
        int cc = blockIdx.x * 32 + tx;
        tile[ty + j * 8][tx] = W[(size_t)rr * Cc + cc];
    }
    __syncthreads();
#pragma unroll
    for (int j = 0; j < 4; ++j) {
        int ro = blockIdx.x * 32 + ty + j * 8;  // row of WT (= col of W)
        int co = blockIdx.y * 32 + tx;          // col of WT (= row of W)
        WT[(size_t)ro * R + co] = f2bf(tile[tx][ty + j * 8]);
    }
}

// ---------------- kernel 3: bf16 GEMM  C[M][Nn] = A[M][K] @ Bt[Nn][K]^T ----------------
// 64x64 tile, 4 waves (2x2), each wave 32x32 via 2x2 MFMA 16x16x32. BK=32.
// EPI: 0 raw f32, 1 raw bf16, 2 tanh bf16, 3 w-decay f32(bias), 4 sigmoid f32(bias), 5 sigmoid bf16
template<int EPI>
__global__ __launch_bounds__(256) void k_gemm(const unsigned short* __restrict__ A,
    const unsigned short* __restrict__ Bt, void* __restrict__ Cp,
    const float* __restrict__ bias, int M, int Nn, int K)
{
    __shared__ unsigned short As[64][40];  // +8 pad -> conflict-light b128
    __shared__ unsigned short Bs[64][40];
    const int t = threadIdx.x, lane = t & 63, wave = t >> 6;
    const int wr = wave >> 1, wc = wave & 1;
    const int bM = blockIdx.y * 64, bN = blockIdx.x * 64;
    const int srow = t >> 2, skc = (t & 3) * 8;
    const int l15 = lane & 15, l16 = lane >> 4;
    f32x4 acc[2][2] = {};

    for (int k0 = 0; k0 < K; k0 += 32) {
        __syncthreads();
        *(int4*)&As[srow][skc] = *(const int4*)(A + (size_t)(bM + srow) * K + k0 + skc);
        *(int4*)&Bs[srow][skc] = *(const int4*)(Bt + (size_t)(bN + srow) * K + k0 + skc);
        __syncthreads();
        bf16x8 af0 = *(const bf16x8*)&As[wr * 32 + l15][l16 * 8];
        bf16x8 af1 = *(const bf16x8*)&As[wr * 32 + 16 + l15][l16 * 8];
        bf16x8 bf0 = *(const bf16x8*)&Bs[wc * 32 + l15][l16 * 8];
        bf16x8 bf1 = *(const bf16x8*)&Bs[wc * 32 + 16 + l15][l16 * 8];
        acc[0][0] = mfma16(af0, bf0, acc[0][0]);
        acc[0][1] = mfma16(af0, bf1, acc[0][1]);
        acc[1][0] = mfma16(af1, bf0, acc[1][0]);
        acc[1][1] = mfma16(af1, bf1, acc[1][1]);
    }

#pragma unroll
    for (int fm = 0; fm < 2; ++fm)
#pragma unroll
        for (int fn = 0; fn < 2; ++fn)
#pragma unroll
            for (int jj = 0; jj < 4; ++jj) {
                int gr = bM + wr * 32 + fm * 16 + l16 * 4 + jj;   // C/D: row=(l>>4)*4+reg
                int gc = bN + wc * 32 + fn * 16 + l15;            //      col=l&15
                float val = acc[fm][fn][jj];
                size_t oi = (size_t)gr * Nn + gc;
                if constexpr (EPI == 0) {
                    ((float*)Cp)[oi] = val;
                } else if constexpr (EPI == 1) {
                    ((unsigned short*)Cp)[oi] = f2bf(val);
                } else if constexpr (EPI == 2) {
                    ((unsigned short*)Cp)[oi] = f2bf(tanhf(val));
                } else if constexpr (EPI == 3) {
                    float z = bias[gc] + val;
                    float sg = 1.f / (1.f + expf(-z));
                    ((float*)Cp)[oi] = expf(-0.60653065971f * sg);  // exp(-exp(w)), w=-softplus(-z)-0.5
                } else if constexpr (EPI == 4) {
                    float z = bias[gc] + val;
                    ((float*)Cp)[oi] = 1.f / (1.f + expf(-z));
                } else {
                    ((unsigned short*)Cp)[oi] = f2bf(1.f / (1.f + expf(-val)));
                }
            }
}

// ---------------- kernel 4: kk normalize + k update (wave per (b,t,h)) ----------------
__global__ __launch_bounds__(256) void k_kproc(float* __restrict__ k, const float* __restrict__ a,
    const float* __restrict__ k_k, const float* __restrict__ k_a, float* __restrict__ kk)
{
    int gw = blockIdx.x * 4 + (threadIdx.x >> 6);
    int lane = threadIdx.x & 63;
    int bt = gw / H_, h = gw - (gw / H_) * H_;
    int c = h * 64 + lane;
    size_t idx = (size_t)bt * C_ + c;
    float kv = k[idx], av = a[idx];
    float kkv = kv * k_k[c];
    float ss = red64(kkv * kkv);
    float inv = 1.f / fmaxf(sqrtf(ss), 1e-12f);
    kk[idx] = kkv * inv;
    k[idx] = kv * (1.f + (av - 1.f) * k_a[c]);
}

// ---------------- kernel 5: serial scan. 1 wave = 4 state rows, lane = column ----------------
__global__ __launch_bounds__(64) void k_scan(const float* __restrict__ r, const float* __restrict__ w,
    const float* __restrict__ k, const float* __restrict__ kk, const float* __restrict__ a,
    const float* __restrict__ v, float* __restrict__ o)
{
    const int bid = blockIdx.x;            // 768 = 48 (b,h) * 16 row-blocks
    const int bh = bid >> 4, iblk = bid & 15;
    const int b = bh / H_, h = bh - (bh / H_) * H_;
    const int i0 = iblk * 4;
    const int j = threadIdx.x;
    size_t p = (size_t)b * T_ * C_ + h * 64;
    float s0 = 0.f, s1 = 0.f, s2 = 0.f, s3 = 0.f;
    for (int t = 0; t < T_; ++t, p += C_) {
        float rj = r[p + j], wj = w[p + j], kj = k[p + j], kkj = kk[p + j], aj = a[p + j];
        const float4 v4 = *(const float4*)(v + p + i0);
        // sa_i = sum_j s_ij * aa_j, aa = -kk  (computed as -(reduce))
        float q0 = s0 * kkj, q1 = s1 * kkj, q2 = s2 * kkj, q3 = s3 * kkj;
        red64_4(q0, q1, q2, q3);
        float bbj = kkj * aj;              // bb = kk * a
        s0 = fmaf(s0, wj, fmaf(-q0, bbj, v4.x * kj));
        s1 = fmaf(s1, wj, fmaf(-q1, bbj, v4.y * kj));
        s2 = fmaf(s2, wj, fmaf(-q2, bbj, v4.z * kj));
        s3 = fmaf(s3, wj, fmaf(-q3, bbj, v4.w * kj));
        float o0 = s0 * rj, o1 = s1 * rj, o2 = s2 * rj, o3 = s3 * rj;
        red64_4(o0, o1, o2, o3);
        if (j == 0) {
            float4 ov; ov.x = o0; ov.y = o1; ov.z = o2; ov.w = o3;
            *(float4*)(o + p + i0) = ov;
        }
    }
}

// ---------------- kernel 6: groupnorm + bonus + gate -> bf16 ----------------
__global__ __launch_bounds__(256) void k_gnorm(const float* __restrict__ o, const float* __restrict__ r,
    const float* __restrict__ k, const float* __restrict__ v, const float* __restrict__ g,
    const float* __restrict__ r_k, const float* __restrict__ gamma, const float* __restrict__ beta,
    unsigned short* __restrict__ yb)
{
    int gw = blockIdx.x * 4 + (threadIdx.x >> 6);
    int lane = threadIdx.x & 63;
    int bt = gw / H_, h = gw - (gw / H_) * H_;
    int c = h * 64 + lane;
    size_t idx = (size_t)bt * C_ + c;
    float ov = o[idx];
    float mean = red64(ov) * 0.015625f;
    float d = ov - mean;
    float var = red64(d * d) * 0.015625f;
    float yn = d * rsqrtf(var + EPS_GN) * gamma[c] + beta[c];
    float dot = red64(r[idx] * k[idx] * r_k[c]);
    float y = (yn + dot * v[idx]) * g[idx];
    yb[idx] = f2bf(y);
}

// ---------------- host ----------------
extern "C" void kernel_launch(void* const* d_in, const int* in_sizes, int n_in,
                              void* d_out, int out_size, void* d_ws, size_t ws_size,
                              hipStream_t stream)
{
    (void)in_sizes; (void)n_in; (void)out_size; (void)ws_size;
    const float* x   = (const float*)d_in[0];
    const float* mr  = (const float*)d_in[1];
    const float* mw  = (const float*)d_in[2];
    const float* mk  = (const float*)d_in[3];
    const float* mv  = (const float*)d_in[4];
    const float* ma  = (const float*)d_in[5];
    const float* mg  = (const float*)d_in[6];
    const float* w0  = (const float*)d_in[7];
    const float* w1  = (const float*)d_in[8];
    const float* w2  = (const float*)d_in[9];
    const float* a0  = (const float*)d_in[10];
    const float* a1  = (const float*)d_in[11];
    const float* a2  = (const float*)d_in[12];
    const float* g1  = (const float*)d_in[13];
    const float* g2  = (const float*)d_in[14];
    const float* k_k = (const float*)d_in[15];
    const float* k_a = (const float*)d_in[16];
    const float* r_k = (const float*)d_in[17];
    const float* Wr  = (const float*)d_in[18];
    const float* Wk  = (const float*)d_in[19];
    const float* Wv  = (const float*)d_in[20];
    const float* Wo  = (const float*)d_in[21];
    const float* gam = (const float*)d_in[22];
    const float* bet = (const float*)d_in[23];

    char* ws = (char*)d_ws;
    constexpr size_t SZF = BTC * 4;   // fp32 [BT][C]
    constexpr size_t SZH = BTC * 2;   // bf16 [BT][C]
    unsigned short* X6 = (unsigned short*)ws;          size_t off = 6 * SZH;
    unsigned short* WrT = (unsigned short*)(ws + off); off += (size_t)768 * 768 * 2;
    unsigned short* WkT = (unsigned short*)(ws + off); off += (size_t)768 * 768 * 2;
    unsigned short* WvT = (unsigned short*)(ws + off); off += (size_t)768 * 768 * 2;
    unsigned short* WoT = (unsigned short*)(ws + off); off += (size_t)768 * 768 * 2;
    unsigned short* w1T = (unsigned short*)(ws + off); off += (size_t)64 * 768 * 2;
    unsigned short* w2T = (unsigned short*)(ws + off); off += (size_t)64 * 768 * 2;
    unsigned short* a1T = (unsigned short*)(ws + off); off += (size_t)64 * 768 * 2;
    unsigned short* a2T = (unsigned short*)(ws + off); off += (size_t)64 * 768 * 2;
    unsigned short* g1T = (unsigned short*)(ws + off); off += (size_t)128 * 768 * 2;
    unsigned short* g2T = (unsigned short*)(ws + off); off += (size_t)128 * 768 * 2;
    float* rbuf  = (float*)(ws + off); off += SZF;
    float* kbuf  = (float*)(ws + off); off += SZF;
    float* vbuf  = (float*)(ws + off); off += SZF;
    float* wdec  = (float*)(ws + off); off += SZF;
    float* abuf  = (float*)(ws + off); off += SZF;
    float* kkbuf = (float*)(ws + off); off += SZF;
    float* gbuf  = (float*)(ws + off); off += SZF;
    unsigned short* hw = (unsigned short*)(ws + off); off += (size_t)4096 * 64 * 2;
    unsigned short* ha = (unsigned short*)(ws + off); off += (size_t)4096 * 64 * 2;
    unsigned short* hg = (unsigned short*)(ws + off); off += (size_t)4096 * 128 * 2;
    // alias: X6 region is dead once all GEMMs consuming it have run
    float* obuf = (float*)ws;                           // [0, SZF)
    unsigned short* ybf = (unsigned short*)(ws + SZF);  // [SZF, SZF+SZH)

    // 1. timeshift + mixes (order: r,w,k,v,a,g)
    k_prep<<<3072, 256, 0, stream>>>(x, mr, mw, mk, mv, ma, mg, X6);
    // 2. weight transposes -> bf16 B^T
    k_transpose<<<dim3(24, 24), 256, 0, stream>>>(Wr, WrT, 768, 768);
    k_transpose<<<dim3(24, 24), 256, 0, stream>>>(Wk, WkT, 768, 768);
    k_transpose<<<dim3(24, 24), 256, 0, stream>>>(Wv, WvT, 768, 768);
    k_transpose<<<dim3(24, 24), 256, 0, stream>>>(Wo, WoT, 768, 768);
    k_transpose<<<dim3(2, 24), 256, 0, stream>>>(w1, w1T, 768, 64);
    k_transpose<<<dim3(24, 2), 256, 0, stream>>>(w2, w2T, 64, 768);
    k_transpose<<<dim3(2, 24), 256, 0, stream>>>(a1, a1T, 768, 64);
    k_transpose<<<dim3(24, 2), 256, 0, stream>>>(a2, a2T, 64, 768);
    k_transpose<<<dim3(4, 24), 256, 0, stream>>>(g1, g1T, 768, 128);
    k_transpose<<<dim3(24, 4), 256, 0, stream>>>(g2, g2T, 128, 768);
    // 3. low-rank chains
    k_gemm<2><<<dim3(1, 64), 256, 0, stream>>>(X6 + 1 * BTC, w1T, hw, nullptr, 4096, 64, 768);   // tanh(xw@w1)
    k_gemm<3><<<dim3(12, 64), 256, 0, stream>>>(hw, w2T, wdec, w0, 4096, 768, 64);               // ws decay
    k_gemm<1><<<dim3(1, 64), 256, 0, stream>>>(X6 + 4 * BTC, a1T, ha, nullptr, 4096, 64, 768);   // xa@a1
    k_gemm<4><<<dim3(12, 64), 256, 0, stream>>>(ha, a2T, abuf, a0, 4096, 768, 64);               // a
    k_gemm<5><<<dim3(2, 64), 256, 0, stream>>>(X6 + 5 * BTC, g1T, hg, nullptr, 4096, 128, 768);  // sig(xg@g1)
    k_gemm<0><<<dim3(12, 64), 256, 0, stream>>>(hg, g2T, gbuf, nullptr, 4096, 768, 128);         // g
    // 4. r,k,v projections
    k_gemm<0><<<dim3(12, 64), 256, 0, stream>>>(X6 + 0 * BTC, WrT, rbuf, nullptr, 4096, 768, 768);
    k_gemm<0><<<dim3(12, 64), 256, 0, stream>>>(X6 + 2 * BTC, WkT, kbuf, nullptr, 4096, 768, 768);
    k_gemm<0><<<dim3(12, 64), 256, 0, stream>>>(X6 + 3 * BTC, WvT, vbuf, nullptr, 4096, 768, 768);
    // 5. kk normalize + k update
    k_kproc<<<12288, 256, 0, stream>>>(kbuf, abuf, k_k, k_a, kkbuf);
    // 6. serial delta-rule scan
    k_scan<<<768, 64, 0, stream>>>(rbuf, wdec, kbuf, kkbuf, abuf, vbuf, obuf);
    // 7. groupnorm + bonus + gate
    k_gnorm<<<12288, 256, 0, stream>>>(obuf, rbuf, kbuf, vbuf, gbuf, r_k, gam, bet, ybf);
    // 8. output projection
    k_gemm<0><<<dim3(12, 64), 256, 0, stream>>>(ybf, WoT, (float*)d_out, nullptr, 4096, 768, 768);
}